// Round 10
// baseline (75.564 us; speedup 1.0000x reference)
//
#include <hip/hip_runtime.h>

// B=8, NA=NB=2048, in=256, D=64
typedef short bf16x8 __attribute__((ext_vector_type(8)));
typedef float f32x4 __attribute__((ext_vector_type(4)));

__device__ __forceinline__ unsigned short f2bf(float x) {
  unsigned u = __float_as_uint(x);
  u += 0x7FFFu + ((u >> 16) & 1u);
  return (unsigned short)(u >> 16);
}

__device__ __forceinline__ void async_copy16(const void* g, void* l) {
  __builtin_amdgcn_global_load_lds(
      (const __attribute__((address_space(1))) void*)g,
      (__attribute__((address_space(3))) void*)l, 16, 0, 0);
}

// ============ zB: z_B^T (bf16) + sB + per-block max(sB) + sA ============
__global__ __launch_bounds__(256) void zb_kernel(
    const float* __restrict__ hB, const float* __restrict__ WB_w,
    const float* __restrict__ WB_b, const float* __restrict__ aB_w,
    const float* __restrict__ aB_b,
    const float* __restrict__ hA, const float* __restrict__ WA_w,
    const float* __restrict__ WA_b, const float* __restrict__ aA_w,
    const float* __restrict__ aA_b,
    unsigned short* __restrict__ zBT, float* __restrict__ sB,
    float* __restrict__ msB_blk, float* __restrict__ sA) {
  __shared__ char wt[32768];   // [64 f][256 k] bf16, 512B rows, XOR swizzle
  __shared__ char hl[16384];   // [32 m][256 k] bf16; reused as zt
  __shared__ float redp[4][16];
  __shared__ float sred[32];
  __shared__ float vAl[256];
  __shared__ float cAl;

  const int t = threadIdx.x, w = t >> 6, l = t & 63;
  const int q = l >> 4, ln = l & 15;
  const int m0g = blockIdx.x * 32;
  const int b = m0g >> 11, mloc = m0g & 2047;

  // ---- sA for global rows m0g..m0g+31 ----
  {
    float sa = 0.f;
    const float4* wr4 = (const float4*)(WA_w + t * 64);
    const float4* aa4 = (const float4*)aA_w;
    #pragma unroll
    for (int i = 0; i < 16; ++i) {
      const float4 x = wr4[i], y = aa4[i];
      sa += x.x * y.x + x.y * y.y + x.z * y.z + x.w * y.w;
    }
    vAl[t] = sa;
    if (t == 0) {
      float ca = aA_b[0];
      for (int f = 0; f < 64; ++f) ca += WA_b[f] * aA_w[f];
      cAl = ca;
    }
    __syncthreads();
    const float4 v4 = ((const float4*)vAl)[l];
    #pragma unroll
    for (int rr = 0; rr < 8; ++rr) {
      const int row = w * 8 + rr;
      const float4 h4 = *(const float4*)(hA + (size_t)(m0g + row) * 256 + l * 4);
      float s = h4.x * v4.x + h4.y * v4.y + h4.z * v4.z + h4.w * v4.w;
      #pragma unroll
      for (int off = 1; off < 64; off <<= 1) s += __shfl_xor(s, off, 64);
      if (l == 0) sA[m0g + row] = s + cAl;
    }
  }

  {  // stage wt[f][k] = bf16(WB_w[k][f])
    const int f = t >> 2, kseg = t & 3;
    #pragma unroll
    for (int j = 0; j < 8; ++j) {
      const int k0 = kseg * 64 + j * 8;
      bf16x8 v;
      #pragma unroll
      for (int jj = 0; jj < 8; ++jj)
        v[jj] = (short)f2bf(WB_w[(k0 + jj) * 64 + f]);
      *(bf16x8*)(wt + ((f * 512 + k0 * 2) ^ ((f & 7) << 4))) = v;
    }
  }
  {  // stage hl[row][k] = bf16(hB[m0g+row][k])
    #pragma unroll
    for (int i = 0; i < 8; ++i) {
      const int idx = i * 1024 + t * 4;
      const int row = idx >> 8, k = idx & 255;
      const float4 x = *(const float4*)(hB + (size_t)m0g * 256 + idx);
      uint2 pk;
      pk.x = (unsigned)f2bf(x.x) | ((unsigned)f2bf(x.y) << 16);
      pk.y = (unsigned)f2bf(x.z) | ((unsigned)f2bf(x.w) << 16);
      *(uint2*)(hl + ((row * 512 + k * 2) ^ ((row & 7) << 4))) = pk;
    }
  }
  __syncthreads();
  const int rt = w & 1, fpair = w >> 1;
  f32x4 acc[2];
  acc[0] = (f32x4){0.f, 0.f, 0.f, 0.f};
  acc[1] = acc[0];
  const int rowA = rt * 16 + ln;
  #pragma unroll
  for (int kk = 0; kk < 8; ++kk) {
    const int ko = kk * 64 + q * 16;
    const bf16x8 a = *(const bf16x8*)(hl + ((rowA * 512 + ko) ^ ((rowA & 7) << 4)));
    #pragma unroll
    for (int j = 0; j < 2; ++j) {
      const int f = fpair * 32 + j * 16 + ln;
      const bf16x8 bb = *(const bf16x8*)(wt + ((f * 512 + ko) ^ ((f & 7) << 4)));
      acc[j] = __builtin_amdgcn_mfma_f32_16x16x32_bf16(a, bb, acc[j], 0, 0, 0);
    }
  }
  float z[2][4];
  float p[4] = {0.f, 0.f, 0.f, 0.f};
  #pragma unroll
  for (int j = 0; j < 2; ++j) {
    const int f = fpair * 32 + j * 16 + ln;
    const float bias = WB_b[f], aw = aB_w[f];
    #pragma unroll
    for (int r = 0; r < 4; ++r) {
      const float zz = acc[j][r] + bias;
      z[j][r] = zz;
      p[r] += zz * aw;
    }
  }
  #pragma unroll
  for (int r = 0; r < 4; ++r) {
    #pragma unroll
    for (int off = 1; off < 16; off <<= 1) p[r] += __shfl_xor(p[r], off, 16);
  }
  if (ln == 0) {
    #pragma unroll
    for (int r = 0; r < 4; ++r) redp[w][q * 4 + r] = p[r];
  }
  __syncthreads();
  char* zt = hl;
  #pragma unroll
  for (int j = 0; j < 2; ++j) {
    const int f = fpair * 32 + j * 16 + ln;
    uint2 pk;
    pk.x = (unsigned)f2bf(z[j][0]) | ((unsigned)f2bf(z[j][1]) << 16);
    pk.y = (unsigned)f2bf(z[j][2]) | ((unsigned)f2bf(z[j][3]) << 16);
    *(uint2*)(zt + f * 80 + (rt * 16 + q * 4) * 2) = pk;
  }
  if (t < 32) {
    const int rtm = t >> 4, mi = t & 15;
    const float s = redp[rtm][mi] + redp[rtm + 2][mi] + aB_b[0];
    sB[m0g + t] = s;
    sred[t] = s;
  }
  __syncthreads();
  if (t == 0) {
    float bm = sred[0];
    #pragma unroll
    for (int i = 1; i < 32; ++i) bm = fmaxf(bm, sred[i]);
    msB_blk[blockIdx.x] = bm;
  }
  {
    const int f = t >> 2, mseg = t & 3;
    const bf16x8 v = *(const bf16x8*)(zt + f * 80 + mseg * 16);
    *(bf16x8*)(zBT + (size_t)b * 131072 + f * 2048 + mloc + mseg * 8) = v;
  }
}

// ============ gat: barrier-free; mask pre-staged to LDS via DMA ============
struct Zc { bf16x8 z0, z1, z2, z3; };

__device__ __forceinline__ uint2 pack_mask32(const int* p) {
  const int4 a = *(const int4*)p;
  const int4 c = *(const int4*)(p + 4);
  uint2 r;
  r.x = (a.x ? 1u : 0u) | (a.y ? 0x100u : 0u) | (a.z ? 0x10000u : 0u) | (a.w ? 0x1000000u : 0u);
  r.y = (c.x ? 1u : 0u) | (c.y ? 0x100u : 0u) | (c.z ? 0x10000u : 0u) | (c.w ? 0x1000000u : 0u);
  return r;
}

__device__ __forceinline__ Zc load_z(const unsigned short* zp0,
    const unsigned short* zp1, const unsigned short* zp2,
    const unsigned short* zp3, const int c) {
  Zc z;
  const int m = c * 32;
  z.z0 = *(const bf16x8*)(zp0 + m);
  z.z1 = *(const bf16x8*)(zp1 + m);
  z.z2 = *(const bf16x8*)(zp2 + m);
  z.z3 = *(const bf16x8*)(zp3 + m);
  return z;
}

__device__ __forceinline__ void gat_compute(const uint2 mk, const Zc& z,
    const float* sBl, const int c, const int lq8, const float sAr, const float M,
    f32x4& a0, f32x4& a1, f32x4& a2, f32x4& a3, float& ds) {
  const int sb0 = c * 32 + lq8;
  const float4 s0 = *(const float4*)(sBl + sb0);
  const float4 s1 = *(const float4*)(sBl + sb0 + 4);
  const float sx[8] = {s0.x, s0.y, s0.z, s0.w, s1.x, s1.y, s1.z, s1.w};
  bf16x8 af;
  #pragma unroll
  for (int j = 0; j < 8; ++j) {
    const unsigned km = ((j < 4 ? mk.x : mk.y) >> (8 * (j & 3))) & 0xFFu;
    const float x = sAr + sx[j];
    const float e = fmaxf(x, 0.01f * x);
    const float v = km ? __expf(e - M) : 0.f;
    af[j] = (short)f2bf(v);
    ds += v;
  }
  a0 = __builtin_amdgcn_mfma_f32_16x16x32_bf16(af, z.z0, a0, 0, 0, 0);
  a1 = __builtin_amdgcn_mfma_f32_16x16x32_bf16(af, z.z1, a1, 0, 0, 0);
  a2 = __builtin_amdgcn_mfma_f32_16x16x32_bf16(af, z.z2, a2, 0, 0, 0);
  a3 = __builtin_amdgcn_mfma_f32_16x16x32_bf16(af, z.z3, a3, 0, 0, 0);
}

template <bool USE8>
__device__ __forceinline__ void gat_main(const char* mll, const int* mp32,
    const unsigned short* zp0, const unsigned short* zp1,
    const unsigned short* zp2, const unsigned short* zp3,
    const float* sBl, const int lq8, const float sAr, const float M,
    f32x4& a0, f32x4& a1, f32x4& a2, f32x4& a3, float& ds) {
  Zc zf[3];
  zf[0] = load_z(zp0, zp1, zp2, zp3, 0);
  zf[1] = load_z(zp0, zp1, zp2, zp3, 1);
  zf[2] = load_z(zp0, zp1, zp2, zp3, 2);
  #pragma unroll
  for (int c = 0; c < 16; ++c) {
    const Zc zc = zf[c % 3];
    if (c + 3 < 16) zf[c % 3] = load_z(zp0, zp1, zp2, zp3, c + 3);
    uint2 mk;
    if constexpr (USE8) mk = *(const uint2*)(mll + c * 512);   // LDS (DMA-staged)
    else mk = pack_mask32(mp32 + c * 32);                      // int32 fallback
    gat_compute(mk, zc, sBl, c, lq8, sAr, M, a0, a1, a2, a3, ds);
  }
}

__global__ __launch_bounds__(128, 4) void gat_kernel(
    const unsigned short* __restrict__ zBT, const float* __restrict__ sA,
    const float* __restrict__ sB, const float* __restrict__ msB_blk,
    const unsigned char* __restrict__ mask8, const int* __restrict__ mask32,
    float* __restrict__ pacc, float* __restrict__ pd) {
  const int b = blockIdx.y, n0 = blockIdx.x * 32, mq = blockIdx.z;
  const int t = threadIdx.x, w = t >> 6, l = t & 63;
  const int ln = l & 15, lq = l >> 4, lq8 = lq * 8;

  __shared__ char maskl[2][8192];  // per-wave [16 chunk][16 row][32 B]
  __shared__ float sBl[512];
  __shared__ unsigned dfl[2];

  // phase 0: mask-dtype detect + sB preload + msB max
  const unsigned vdet = mask8[t * 4 + 1];  // always 0 for int32/fp32 0/1
  const unsigned long long bal = __ballot(vdet != 0);
  if (l == 0) dfl[w] = (bal != 0ull) ? 1u : 0u;
  ((float4*)sBl)[t] = ((const float4*)(sB + b * 2048 + mq * 512))[t];
  float mb = msB_blk[b * 64 + l];
  #pragma unroll
  for (int off = 1; off < 64; off <<= 1) mb = fmaxf(mb, __shfl_xor(mb, off, 64));
  __syncthreads();
  const bool use8 = (dfl[0] | dfl[1]) != 0;

  const int row = n0 + w * 16 + ln;
  const float sAr = sA[b * 2048 + row];
  const float Mf = sAr + mb;
  const float M = fmaxf(Mf, 0.01f * Mf);  // leaky monotone: upper bound on scores

  // Issue the wave's entire mask slice as 8 async DMAs (16 rows x 512 B).
  // Lane mapping: DMA k, lane l -> LDS byte k*1024 + l*16
  //   = chunk c = 2k + (l>>5), row (l&31)>>1, mcol (l&1)*16
  // Global source: row-major mask; lanes l and l+32 cover one 64B line.
  char* mslice = maskl[w];
  {
    const unsigned char* mrowbase =
        mask8 + ((size_t)(b * 2048 + n0 + w * 16)) * 2048 + mq * 512;
    const unsigned char* gp0 =
        mrowbase + (size_t)((l & 31) >> 1) * 2048 + (l >> 5) * 32 + (l & 1) * 16;
    #pragma unroll
    for (int k = 0; k < 8; ++k)
      async_copy16(gp0 + k * 64, mslice + k * 1024);
  }
  asm volatile("s_waitcnt vmcnt(0)" ::: "memory");
  __builtin_amdgcn_sched_barrier(0);

  float ds = 0.f;
  f32x4 a0 = (f32x4){0.f, 0.f, 0.f, 0.f}, a1 = a0, a2 = a0, a3 = a0;

  const size_t mbase = ((size_t)(b * 2048 + row)) * 2048 + mq * 512 + lq8;
  const int* mp32 = mask32 + mbase;
  const unsigned short* zp0 = zBT + ((size_t)(b * 64 + ln)) * 2048 + mq * 512 + lq8;
  const unsigned short* zp1 = zp0 + 16 * 2048;
  const unsigned short* zp2 = zp0 + 32 * 2048;
  const unsigned short* zp3 = zp0 + 48 * 2048;
  const char* mll = mslice + ln * 32 + lq8;

  if (use8) gat_main<true>(mll, mp32, zp0, zp1, zp2, zp3, sBl, lq8, sAr, M, a0, a1, a2, a3, ds);
  else      gat_main<false>(mll, mp32, zp0, zp1, zp2, zp3, sBl, lq8, sAr, M, a0, a1, a2, a3, ds);

  // epilogue: row denominators + partial store
  ds += __shfl_xor(ds, 16, 64);
  ds += __shfl_xor(ds, 32, 64);
  if (l < 16) pd[(size_t)(mq * 8 + b) * 2048 + n0 + w * 16 + l] = ds;
  const size_t obase = ((size_t)(mq * 8 + b) * 2048 + n0 + w * 16 + lq * 4) * 64 + ln;
  #pragma unroll
  for (int r = 0; r < 4; ++r) {
    float* o = pacc + obase + (size_t)r * 64;
    o[0] = a0[r];
    o[16] = a1[r];
    o[32] = a2[r];
    o[48] = a3[r];
  }
}

// ============ merge: out = Σ pacc / Σ pd ============
__global__ __launch_bounds__(256) void merge_kernel(
    const float* __restrict__ pacc, const float* __restrict__ pd,
    float* __restrict__ out) {
  const int tid = blockIdx.x * 256 + threadIdx.x;  // float4 units: 262144
  const int bn = tid >> 4;
  const float4* p4 = (const float4*)pacc;
  const float4 x0 = p4[tid], x1 = p4[262144 + tid];
  const float4 x2 = p4[524288 + tid], x3 = p4[786432 + tid];
  const float d = pd[bn] + pd[16384 + bn] + pd[32768 + bn] + pd[49152 + bn];
  const float inv = d > 0.f ? 1.f / d : 0.f;
  float4 o;
  o.x = (x0.x + x1.x + x2.x + x3.x) * inv;
  o.y = (x0.y + x1.y + x2.y + x3.y) * inv;
  o.z = (x0.z + x1.z + x2.z + x3.z) * inv;
  o.w = (x0.w + x1.w + x2.w + x3.w) * inv;
  ((float4*)out)[tid] = o;
}

extern "C" void kernel_launch(void* const* d_in, const int* in_sizes, int n_in,
                              void* d_out, int out_size, void* d_ws, size_t ws_size,
                              hipStream_t stream) {
  const float* h_A = (const float*)d_in[0];
  const float* h_B = (const float*)d_in[1];
  const unsigned char* mask8 = (const unsigned char*)d_in[2];
  const int* mask32 = (const int*)d_in[2];
  const float* WA_w = (const float*)d_in[3];
  const float* WA_b = (const float*)d_in[4];
  const float* WB_w = (const float*)d_in[5];
  const float* WB_b = (const float*)d_in[6];
  const float* aA_w = (const float*)d_in[7];
  const float* aA_b = (const float*)d_in[8];
  const float* aB_w = (const float*)d_in[9];
  const float* aB_b = (const float*)d_in[10];
  float* out = (float*)d_out;

  char* wsb = (char*)d_ws;
  unsigned short* zBT = (unsigned short*)wsb;        // 2,097,152 B
  float* sB      = (float*)(wsb + 2097152);          // 65,536 B
  float* sA      = (float*)(wsb + 2162688);          // 65,536 B
  float* msB_blk = (float*)(wsb + 2228224);          // 2,048 B
  float* pacc    = (float*)(wsb + 2230272);          // 16,777,216 B
  float* pd      = (float*)(wsb + 19007488);         // 262,144 B

  zb_kernel<<<512, 256, 0, stream>>>(h_B, WB_w, WB_b, aB_w, aB_b,
                                     h_A, WA_w, WA_b, aA_w, aA_b,
                                     zBT, sB, msB_blk, sA);
  gat_kernel<<<dim3(64, 8, 4), 128, 0, stream>>>(zBT, sA, sB, msB_blk,
                                                 mask8, mask32, pacc, pd);
  merge_kernel<<<1024, 256, 0, stream>>>(pacc, pd, out);
}

// Round 11
// 72.270 us; speedup vs baseline: 1.0456x; 1.0456x over previous
//
#include <hip/hip_runtime.h>

// B=8, NA=NB=2048, in=256, D=64
typedef short bf16x8 __attribute__((ext_vector_type(8)));
typedef float f32x4 __attribute__((ext_vector_type(4)));

__device__ __forceinline__ unsigned short f2bf(float x) {
  unsigned u = __float_as_uint(x);
  u += 0x7FFFu + ((u >> 16) & 1u);
  return (unsigned short)(u >> 16);
}

// ===== kernel 1: blocks 0..511 = zB GEMM (+sB, msB, sA); 512..1023 = mask pack =====
// Packed layout: pk[row][ (m8&15)*16 + (m8>>4) ], m8 = m/8. A gat thread with
// q0 = 4*mg+lq reads bytes [q0*16 .. q0*16+16) = chunks cc=0..15 as ONE uint4.
__global__ __launch_bounds__(256) void zbpack_kernel(
    const float* __restrict__ hB, const float* __restrict__ WB_w,
    const float* __restrict__ WB_b, const float* __restrict__ aB_w,
    const float* __restrict__ aB_b,
    const float* __restrict__ hA, const float* __restrict__ WA_w,
    const float* __restrict__ WA_b, const float* __restrict__ aA_w,
    const float* __restrict__ aA_b,
    const unsigned char* __restrict__ mask8, const int* __restrict__ mask32,
    unsigned short* __restrict__ zBT, float* __restrict__ sB,
    float* __restrict__ msB_blk, float* __restrict__ sA,
    unsigned char* __restrict__ packed) {
  const int t = threadIdx.x, w = t >> 6, l = t & 63;

  if (blockIdx.x >= 512) {
    // ---------------- mask bit-pack: 32 rows per block ----------------
    __shared__ unsigned char pbuf[8192];
    __shared__ unsigned pdfl[4];
    const int p = blockIdx.x - 512;
    // per-block dtype detect: bytes at global offset o, o%4==1, within bool size
    const unsigned vdet = mask8[(size_t)p * 65536 + t * 256 + 1];
    const unsigned long long bal = __ballot(vdet != 0);
    if (l == 0) pdfl[w] = (bal != 0ull) ? 1u : 0u;
    __syncthreads();
    const bool use8 = (pdfl[0] | pdfl[1] | pdfl[2] | pdfl[3]) != 0;
    #pragma unroll 4
    for (int i = 0; i < 32; ++i) {
      const int bi = i * 256 + t;
      const int row = bi >> 8, m8 = bi & 255;
      unsigned byte = 0;
      if (use8) {
        const uint2 v = *(const uint2*)(mask8 + ((size_t)(p * 32 + row)) * 2048 + m8 * 8);
        #pragma unroll
        for (int j = 0; j < 4; ++j) {
          byte |= ((v.x >> (8 * j)) & 0xFFu) ? (1u << j) : 0u;
          byte |= ((v.y >> (8 * j)) & 0xFFu) ? (1u << (j + 4)) : 0u;
        }
      } else {
        const int* s32 = mask32 + ((size_t)(p * 32 + row)) * 2048 + m8 * 8;
        const int4 v1 = *(const int4*)s32;
        const int4 v2 = *(const int4*)(s32 + 4);
        byte |= (v1.x ? 1u : 0u) | (v1.y ? 2u : 0u) | (v1.z ? 4u : 0u) | (v1.w ? 8u : 0u);
        byte |= (v2.x ? 16u : 0u) | (v2.y ? 32u : 0u) | (v2.z ? 64u : 0u) | (v2.w ? 128u : 0u);
      }
      pbuf[row * 256 + (m8 & 15) * 16 + (m8 >> 4)] = (unsigned char)byte;
    }
    __syncthreads();
    #pragma unroll
    for (int k = 0; k < 2; ++k) {
      const int oi = t * 2 + k;
      *(uint4*)(packed + (size_t)p * 8192 + oi * 16) = *(const uint4*)(pbuf + oi * 16);
    }
    return;
  }

  // ---------------- zB GEMM (unchanged structure) ----------------
  __shared__ char wt[32768];
  __shared__ char hl[16384];
  __shared__ float redp[4][16];
  __shared__ float sred[32];
  __shared__ float vAl[256];
  __shared__ float cAl;

  const int q = l >> 4, ln = l & 15;
  const int m0g = blockIdx.x * 32;
  const int b = m0g >> 11, mloc = m0g & 2047;

  {  // sA for rows m0g..m0g+31
    float sa = 0.f;
    const float4* wr4 = (const float4*)(WA_w + t * 64);
    const float4* aa4 = (const float4*)aA_w;
    #pragma unroll
    for (int i = 0; i < 16; ++i) {
      const float4 x = wr4[i], y = aa4[i];
      sa += x.x * y.x + x.y * y.y + x.z * y.z + x.w * y.w;
    }
    vAl[t] = sa;
    if (t == 0) {
      float ca = aA_b[0];
      for (int f = 0; f < 64; ++f) ca += WA_b[f] * aA_w[f];
      cAl = ca;
    }
    __syncthreads();
    const float4 v4 = ((const float4*)vAl)[l];
    #pragma unroll
    for (int rr = 0; rr < 8; ++rr) {
      const int row = w * 8 + rr;
      const float4 h4 = *(const float4*)(hA + (size_t)(m0g + row) * 256 + l * 4);
      float s = h4.x * v4.x + h4.y * v4.y + h4.z * v4.z + h4.w * v4.w;
      #pragma unroll
      for (int off = 1; off < 64; off <<= 1) s += __shfl_xor(s, off, 64);
      if (l == 0) sA[m0g + row] = s + cAl;
    }
  }
  {  // wt[f][k] = bf16(WB_w[k][f])
    const int f = t >> 2, kseg = t & 3;
    #pragma unroll
    for (int j = 0; j < 8; ++j) {
      const int k0 = kseg * 64 + j * 8;
      bf16x8 v;
      #pragma unroll
      for (int jj = 0; jj < 8; ++jj)
        v[jj] = (short)f2bf(WB_w[(k0 + jj) * 64 + f]);
      *(bf16x8*)(wt + ((f * 512 + k0 * 2) ^ ((f & 7) << 4))) = v;
    }
  }
  {  // hl[row][k] = bf16(hB[m0g+row][k])
    #pragma unroll
    for (int i = 0; i < 8; ++i) {
      const int idx = i * 1024 + t * 4;
      const int row = idx >> 8, k = idx & 255;
      const float4 x = *(const float4*)(hB + (size_t)m0g * 256 + idx);
      uint2 pk;
      pk.x = (unsigned)f2bf(x.x) | ((unsigned)f2bf(x.y) << 16);
      pk.y = (unsigned)f2bf(x.z) | ((unsigned)f2bf(x.w) << 16);
      *(uint2*)(hl + ((row * 512 + k * 2) ^ ((row & 7) << 4))) = pk;
    }
  }
  __syncthreads();
  const int rt = w & 1, fpair = w >> 1;
  f32x4 acc[2];
  acc[0] = (f32x4){0.f, 0.f, 0.f, 0.f};
  acc[1] = acc[0];
  const int rowA = rt * 16 + ln;
  #pragma unroll
  for (int kk = 0; kk < 8; ++kk) {
    const int ko = kk * 64 + q * 16;
    const bf16x8 a = *(const bf16x8*)(hl + ((rowA * 512 + ko) ^ ((rowA & 7) << 4)));
    #pragma unroll
    for (int j = 0; j < 2; ++j) {
      const int f = fpair * 32 + j * 16 + ln;
      const bf16x8 bb = *(const bf16x8*)(wt + ((f * 512 + ko) ^ ((f & 7) << 4)));
      acc[j] = __builtin_amdgcn_mfma_f32_16x16x32_bf16(a, bb, acc[j], 0, 0, 0);
    }
  }
  float z[2][4];
  float p[4] = {0.f, 0.f, 0.f, 0.f};
  #pragma unroll
  for (int j = 0; j < 2; ++j) {
    const int f = fpair * 32 + j * 16 + ln;
    const float bias = WB_b[f], aw = aB_w[f];
    #pragma unroll
    for (int r = 0; r < 4; ++r) {
      const float zz = acc[j][r] + bias;
      z[j][r] = zz;
      p[r] += zz * aw;
    }
  }
  #pragma unroll
  for (int r = 0; r < 4; ++r) {
    #pragma unroll
    for (int off = 1; off < 16; off <<= 1) p[r] += __shfl_xor(p[r], off, 16);
  }
  if (ln == 0) {
    #pragma unroll
    for (int r = 0; r < 4; ++r) redp[w][q * 4 + r] = p[r];
  }
  __syncthreads();
  char* zt = hl;
  #pragma unroll
  for (int j = 0; j < 2; ++j) {
    const int f = fpair * 32 + j * 16 + ln;
    uint2 pk;
    pk.x = (unsigned)f2bf(z[j][0]) | ((unsigned)f2bf(z[j][1]) << 16);
    pk.y = (unsigned)f2bf(z[j][2]) | ((unsigned)f2bf(z[j][3]) << 16);
    *(uint2*)(zt + f * 80 + (rt * 16 + q * 4) * 2) = pk;
  }
  if (t < 32) {
    const int rtm = t >> 4, mi = t & 15;
    const float s = redp[rtm][mi] + redp[rtm + 2][mi] + aB_b[0];
    sB[m0g + t] = s;
    sred[t] = s;
  }
  __syncthreads();
  if (t == 0) {
    float bm = sred[0];
    #pragma unroll
    for (int i = 1; i < 32; ++i) bm = fmaxf(bm, sred[i]);
    msB_blk[blockIdx.x] = bm;
  }
  {
    const int f = t >> 2, mseg = t & 3;
    const bf16x8 v = *(const bf16x8*)(zt + f * 80 + mseg * 16);
    *(bf16x8*)(zBT + (size_t)b * 131072 + f * 2048 + mloc + mseg * 8) = v;
  }
}

// ===== kernel 2: gat — mask in 4 VGPRs, z from L2, full rows, no merge =====
struct Z4 { bf16x8 z0, z1, z2, z3; };

__device__ __forceinline__ Z4 ldz(const unsigned short* z0p, const unsigned short* z1p,
                                  const unsigned short* z2p, const unsigned short* z3p,
                                  const int mo) {
  Z4 z;
  z.z0 = *(const bf16x8*)(z0p + mo);
  z.z1 = *(const bf16x8*)(z1p + mo);
  z.z2 = *(const bf16x8*)(z2p + mo);
  z.z3 = *(const bf16x8*)(z3p + mo);
  return z;
}

__device__ __forceinline__ void gat_compute(const Z4& z, const unsigned mkb,
    const float* sBl, const int mo, const float sAr, const float M,
    f32x4& a0, f32x4& a1, f32x4& a2, f32x4& a3, float& ds) {
  const float4 s0 = *(const float4*)(sBl + mo);
  const float4 s1 = *(const float4*)(sBl + mo + 4);
  const float sx[8] = {s0.x, s0.y, s0.z, s0.w, s1.x, s1.y, s1.z, s1.w};
  bf16x8 af;
  #pragma unroll
  for (int j = 0; j < 8; ++j) {
    const float x = sAr + sx[j];
    const float e = fmaxf(x, 0.01f * x);
    const float v = ((mkb >> j) & 1u) ? __expf(e - M) : 0.f;
    af[j] = (short)f2bf(v);
    ds += v;
  }
  a0 = __builtin_amdgcn_mfma_f32_16x16x32_bf16(af, z.z0, a0, 0, 0, 0);
  a1 = __builtin_amdgcn_mfma_f32_16x16x32_bf16(af, z.z1, a1, 0, 0, 0);
  a2 = __builtin_amdgcn_mfma_f32_16x16x32_bf16(af, z.z2, a2, 0, 0, 0);
  a3 = __builtin_amdgcn_mfma_f32_16x16x32_bf16(af, z.z3, a3, 0, 0, 0);
}

__global__ __launch_bounds__(512, 4) void gat_kernel(
    const unsigned short* __restrict__ zBT, const float* __restrict__ sA,
    const float* __restrict__ sB, const float* __restrict__ msB_blk,
    const unsigned char* __restrict__ packed, float* __restrict__ out) {
  const int b = blockIdx.y, n0 = blockIdx.x * 32;
  const int t = threadIdx.x, w = t >> 6, l = t & 63;
  const int rg = w & 1, mg = w >> 1;     // row-group, m-group
  const int ln = l & 15, lq = l >> 4;

  __shared__ float sBl[2048];            // 8 KB
  __shared__ float buf[4 * 32 * 64];     // 32 KB partial acc [mg][row32][f64]
  __shared__ float dpart[4][32];

  ((float4*)sBl)[t] = ((const float4*)(sB + b * 2048))[t];
  float mb = msB_blk[b * 64 + l];
  #pragma unroll
  for (int off = 1; off < 64; off <<= 1) mb = fmaxf(mb, __shfl_xor(mb, off, 64));
  __syncthreads();

  const int arow = rg * 16 + ln;         // this lane's w-row (A-frag row)
  const float sAr = sA[b * 2048 + n0 + arow];
  const float Mf = sAr + mb;
  const float M = fmaxf(Mf, 0.01f * Mf); // leaky monotone: safe upper bound
  // entire mask need of this thread: one uint4 (16 chunk-bytes)
  const uint4 mk = *(const uint4*)(packed +
      ((size_t)(b * 2048 + n0 + arow)) * 256 + (4 * mg + lq) * 16);

  const unsigned short* z0p = zBT + (size_t)b * 131072 + ln * 2048;
  const unsigned short* z1p = z0p + 32768;
  const unsigned short* z2p = z0p + 65536;
  const unsigned short* z3p = z0p + 98304;
  const int mbase = mg * 32 + lq * 8;    // + cc*128

  float ds = 0.f;
  f32x4 a0 = (f32x4){0.f, 0.f, 0.f, 0.f}, a1 = a0, a2 = a0, a3 = a0;

  // 16 chunks, 2-deep ping-pong register pipeline, zero barriers
  Z4 zA = ldz(z0p, z1p, z2p, z3p, mbase);
  Z4 zB;
  #pragma unroll
  for (int cc = 0; cc < 16; cc += 2) {
    const unsigned mka =
        ((cc & 2) ? ((cc & 4) ? ((cc & 8) ? mk.w : mk.y) : ((cc & 8) ? mk.z : mk.x))
                  : ((cc & 4) ? ((cc & 8) ? mk.w : mk.y) : ((cc & 8) ? mk.z : mk.x)));
    // cc even: byte index cc -> dword cc>>2, shift (cc&3)*8
    const unsigned dw0 = (cc >> 2) == 0 ? mk.x : (cc >> 2) == 1 ? mk.y : (cc >> 2) == 2 ? mk.z : mk.w;
    const unsigned dw1 = ((cc + 1) >> 2) == 0 ? mk.x : ((cc + 1) >> 2) == 1 ? mk.y : ((cc + 1) >> 2) == 2 ? mk.z : mk.w;
    (void)mka;
    if (cc + 1 < 16) zB = ldz(z0p, z1p, z2p, z3p, mbase + (cc + 1) * 128);
    gat_compute(zA, (dw0 >> ((cc & 3) * 8)) & 0xFFu, sBl, mbase + cc * 128,
                sAr, M, a0, a1, a2, a3, ds);
    if (cc + 2 < 16) zA = ldz(z0p, z1p, z2p, z3p, mbase + (cc + 2) * 128);
    gat_compute(zB, (dw1 >> (((cc + 1) & 3) * 8)) & 0xFFu, sBl, mbase + (cc + 1) * 128,
                sAr, M, a0, a1, a2, a3, ds);
  }

  // denominators: reduce over lq (lanes l^16, l^32 share arow)
  ds += __shfl_xor(ds, 16, 64);
  ds += __shfl_xor(ds, 32, 64);
  if (l < 16) dpart[mg][rg * 16 + l] = ds;
  // partial acc -> LDS  (D frag: row = lq*4+r, col = fg*16+ln)
  #pragma unroll
  for (int r = 0; r < 4; ++r) {
    const int orow = rg * 16 + lq * 4 + r;
    buf[(mg * 32 + orow) * 64 + ln]      = a0[r];
    buf[(mg * 32 + orow) * 64 + 16 + ln] = a1[r];
    buf[(mg * 32 + orow) * 64 + 32 + ln] = a2[r];
    buf[(mg * 32 + orow) * 64 + 48 + ln] = a3[r];
  }
  __syncthreads();
  // final: sum 4 m-group partials, divide, store (coalesced float4)
  {
    const int row = t >> 4, f0 = (t & 15) * 4;
    const float4 p0 = *(const float4*)(buf + (0 * 32 + row) * 64 + f0);
    const float4 p1 = *(const float4*)(buf + (1 * 32 + row) * 64 + f0);
    const float4 p2 = *(const float4*)(buf + (2 * 32 + row) * 64 + f0);
    const float4 p3 = *(const float4*)(buf + (3 * 32 + row) * 64 + f0);
    const float d = dpart[0][row] + dpart[1][row] + dpart[2][row] + dpart[3][row];
    const float inv = d > 0.f ? 1.f / d : 0.f;
    float4 o;
    o.x = (p0.x + p1.x + p2.x + p3.x) * inv;
    o.y = (p0.y + p1.y + p2.y + p3.y) * inv;
    o.z = (p0.z + p1.z + p2.z + p3.z) * inv;
    o.w = (p0.w + p1.w + p2.w + p3.w) * inv;
    *(float4*)(out + ((size_t)(b * 2048 + n0 + row)) * 64 + f0) = o;
  }
}

extern "C" void kernel_launch(void* const* d_in, const int* in_sizes, int n_in,
                              void* d_out, int out_size, void* d_ws, size_t ws_size,
                              hipStream_t stream) {
  const float* h_A = (const float*)d_in[0];
  const float* h_B = (const float*)d_in[1];
  const unsigned char* mask8 = (const unsigned char*)d_in[2];
  const int* mask32 = (const int*)d_in[2];
  const float* WA_w = (const float*)d_in[3];
  const float* WA_b = (const float*)d_in[4];
  const float* WB_w = (const float*)d_in[5];
  const float* WB_b = (const float*)d_in[6];
  const float* aA_w = (const float*)d_in[7];
  const float* aA_b = (const float*)d_in[8];
  const float* aB_w = (const float*)d_in[9];
  const float* aB_b = (const float*)d_in[10];
  float* out = (float*)d_out;

  char* wsb = (char*)d_ws;
  unsigned short* zBT    = (unsigned short*)wsb;       // 2,097,152 B
  float* sB              = (float*)(wsb + 2097152);    // 65,536 B
  float* sA              = (float*)(wsb + 2162688);    // 65,536 B
  float* msB_blk         = (float*)(wsb + 2228224);    // 2,048 B
  unsigned char* packed  = (unsigned char*)(wsb + 2230272);  // 4,194,304 B

  zbpack_kernel<<<1024, 256, 0, stream>>>(h_B, WB_w, WB_b, aB_w, aB_b,
                                          h_A, WA_w, WA_b, aA_w, aA_b,
                                          mask8, mask32,
                                          zBT, sB, msB_blk, sA, packed);
  gat_kernel<<<dim3(64, 8), 512, 0, stream>>>(zBT, sA, sB, msB_blk, packed, out);
}